// Round 7
// baseline (669.887 us; speedup 1.0000x reference)
//
#include <hip/hip_runtime.h>
#include <hip/hip_bf16.h>

#define DI __device__ __forceinline__

// ---------- bf16 helpers (raw ushort bits) ----------
DI float b2f(unsigned short u) {
    union { unsigned int i; float f; } x; x.i = ((unsigned int)u) << 16; return x.f;
}
DI unsigned short f2b(float f) {
    union { float f; unsigned int i; } x; x.f = f;
    unsigned int r = x.i + 0x7fff + ((x.i >> 16) & 1);  // RNE
    return (unsigned short)(r >> 16);
}
// flavor-aware input load: f32!=0 -> fp32 array, else bf16 array
DI float ldin(const void* p, long i, int f32) {
    return f32 ? ((const float*)p)[i] : b2f(((const unsigned short*)p)[i]);
}
DI void stval(float* p, float v) { *p = v; }
DI void stval(unsigned short* p, float v) { *p = f2b(v); }

// ---------- constants ----------
static constexpr int N1 = 30000, N2 = 15000, R = 5;
static constexpr int IN = 128, HC0 = 256, C1 = 40;
static constexpr float NEGBIG = -1e30f;    // finite "-inf" (NaN-proof masking)
static constexpr int LDK = 64;             // LDS K-stride (shorts); row = 128B

typedef short bf16x8 __attribute__((ext_vector_type(8)));
typedef float f32x4 __attribute__((ext_vector_type(4)));

// ---------- dtype flavor detection (fp32 read as bf16 -> huge/NaN exponents) ----------
__global__ void detect_k(const void* emb, int* flag)
{
    int lane = threadIdx.x;   // 64 threads
    int bad = 0;
    for (int j = 0; j < 4; ++j) {
        float f = b2f(((const unsigned short*)emb)[lane * 4 + j]);
        if (!(fabsf(f) < 1e8f)) bad = 1;   // catches NaN too
    }
    unsigned long long anybad = __ballot(bad != 0);
    if (lane == 0) *flag = (anybad != 0ull) ? 1 : 0;
}

// ---------- fused prep: 12 weight transposes + alpha-GEMM B matrices + cnt zero ----------
// transpose job y: dst[b][n][k] = bf16(src[b][k][n])
struct PrepJobs {
    const void* src[12];
    unsigned short* dst[12];
    int K[12];
    int N[12];
    int per[12];
};
__global__ __launch_bounds__(256) void prep_all_k(
    PrepJobs J,
    const void* aj0, const void* ai0, const void* aj1, const void* ai1,
    unsigned short* A0j, unsigned short* A0i, unsigned short* A1j, unsigned short* A1i,
    int* __restrict__ cnt, int cntn,
    const int* __restrict__ dflag)
{
    const int f32 = *dflag;
    const int y = blockIdx.y;
    long t = (long)blockIdx.x * 256 + threadIdx.x;
    if (y < 12) {
        if (t >= J.per[y]) return;
        const int K = J.K[y], N = J.N[y];
        long kn = (long)K * N;
        long b = t / kn, rem = t % kn;
        long k = rem / N, n = rem % N;          // t fastest over n -> coalesced read
        J.dst[y][(b * N + n) * K + k] = f2b(ldin(J.src[y], t, f32));
    } else {
        // att matrices: A0j[j=r*4+h][k] = attj0[r,h,c] if k==h*64+c else 0 (20x256)
        if (t < 20 * 256) {
            int j = (int)(t >> 8), k = (int)(t & 255);
            int h = j & 3, r = j >> 2;
            bool on = (k >> 6) == h;
            A0j[t] = f2b(on ? ldin(aj0, r * 256 + k, f32) : 0.f);
            A0i[t] = f2b(on ? ldin(ai0, r * 256 + k, f32) : 0.f);
        }
        if (t < 5 * 40) {
            A1j[t] = f2b(ldin(aj1, t, f32));
            A1i[t] = f2b(ldin(ai1, t, f32));
        }
        if (t < cntn) cnt[t] = 0;
    }
}

// ---------- gather x[:N1] = bf16(emb[lidx[n_id[n]]]) ----------
__global__ __launch_bounds__(256) void gather_k(
    const int* __restrict__ n_id, const int* __restrict__ lidx,
    const void* __restrict__ emb, unsigned short* __restrict__ x, int rows,
    const int* __restrict__ dflag)
{
    const int f32 = *dflag;
    long t = (long)blockIdx.x * 256 + threadIdx.x;
    long n = t >> 7, d = t & 127;
    if (n >= rows) return;
    long row = lidx[n_id[n]];
    x[n * IN + d] = f2b(ldin(emb, row * IN + d, f32));
}

// ---------- MFMA GEMM cores ----------
// LDS layouts are XOR-swizzled (T2, G4): element (row, 16B-slot s) lives at
// slot s ^ (row&7). global_load_lds writes linearly (lane*16B), so fast staging
// pre-swizzles the per-lane GLOBAL source address (rule #21); slow staging
// swizzles its direct LDS writes; fragment reads apply the same XOR.

DI void gload_lds16(const unsigned short* src, unsigned short* dst)
{
    __builtin_amdgcn_global_load_lds(
        (const __attribute__((address_space(1))) unsigned int*)src,
        (__attribute__((address_space(3))) unsigned int*)dst, 16, 0, 0);
}

// Stage one [128 rows][64 cols] K-chunk with 4 waves (generic GEMM tiles)
DI void stage_fast(const unsigned short* __restrict__ G, int K,
                   unsigned short* S, int wave, int lane)
{
    const int p = lane >> 3;                       // row-within-8 (== row&7)
    const int scol = ((lane & 7) ^ p) * 8;         // pre-swizzled source col (shorts)
#pragma unroll
    for (int t = 0; t < 4; ++t) {
        int row = t * 32 + wave * 8 + p;
        gload_lds16(G + (long)row * K + scol, S + (t * 32 + wave * 8) * LDK);
    }
}
// Stage one [128 rows][64 cols] K-chunk with 16 waves (1 call/lane)
DI void stage_fast16(const unsigned short* __restrict__ G, int K,
                     unsigned short* S, int wave, int lane)
{
    const int p = lane >> 3;
    const int scol = ((lane & 7) ^ p) * 8;
    int row = wave * 8 + p;                        // row&7 == p
    gload_lds16(G + (long)row * K + scol, S + (wave * 8) * LDK);
}
// Slow staging (boundary rows / ragged K): guarded, zero-filled, swizzled writes
DI void stage_slow(const unsigned short* __restrict__ G, int rows, int K,
                   int r0, int k0, unsigned short* S, int tid)
{
    const int sr = tid >> 1, sq = (tid & 1) * 32;
    const int sx = sr & 7;
    unsigned short* drow = S + sr * LDK;
    const unsigned short* g = G + (long)(r0 + sr) * K + k0 + sq;
    const bool rowok = (r0 + sr) < rows;
    const int s0 = sq >> 3;                        // base 16B slot (0 or 4)
    if (rowok && (k0 + sq + 32) <= K) {
        const uint4* gv = (const uint4*)g;
        uint4 a = gv[0], b = gv[1], c = gv[2], d = gv[3];
        *(uint4*)(drow + (((s0 + 0) ^ sx) << 3)) = a;
        *(uint4*)(drow + (((s0 + 1) ^ sx) << 3)) = b;
        *(uint4*)(drow + (((s0 + 2) ^ sx) << 3)) = c;
        *(uint4*)(drow + (((s0 + 3) ^ sx) << 3)) = d;
    } else if (!rowok) {
        uint4 zz = {0u, 0u, 0u, 0u};
        *(uint4*)(drow + (((s0 + 0) ^ sx) << 3)) = zz;
        *(uint4*)(drow + (((s0 + 1) ^ sx) << 3)) = zz;
        *(uint4*)(drow + (((s0 + 2) ^ sx) << 3)) = zz;
        *(uint4*)(drow + (((s0 + 3) ^ sx) << 3)) = zz;
    } else {
#pragma unroll 8
        for (int j = 0; j < 32; ++j) {
            int col = sq + j;
            int k = k0 + col;
            int widx = (((col >> 3) ^ sx) << 3) | (col & 7);
            drow[widx] = (k < K) ? g[j] : (unsigned short)0;
        }
    }
}

// ---------- A-resident 3-way GEMM, 16-wave counted-vmcnt pipeline ----------
// 1024 threads (16 waves), 128x128 tile, K template {128,256}.
// A-tile (shared by all 3 sel) staged to LDS ONCE full-K. B staged per 64-col
// chunk into a 2x16KB double buffer, ONE gload/lane/chunk. Per chunk:
//   issue next-chunk prefetch -> s_waitcnt vmcnt(1) -> s_barrier -> MFMA -> s_barrier
// The prefetch stays in flight across the barriers (T4: never drain mid-loop);
// occupancy cost of the 96KB LDS is offset by 16 waves/block (16 waves/CU at
// K=256, 32 waves/CU at K=128 -- same or better than r6's ares4).
// No early returns (all threads reach every barrier). stageA may read up to 127
// rows past M for boundary tiles -- callers guarantee trailing workspace;
// garbage rows never written out (gr<M guard).
template <int KK>
__global__ __launch_bounds__(1024) void gemm_ares5_k(
    const unsigned short* __restrict__ Ab,
    const unsigned short* B0, const unsigned short* B1, const unsigned short* B2,
    unsigned short* C0, unsigned short* C1, unsigned short* C2,
    const void* bias0, const void* bias1, const void* bias2,
    const int* __restrict__ dflag,
    int M, long sA, long sB, long sC)
{
    __shared__ unsigned short As[128 * KK];      // 64KB (K=256) / 32KB (K=128)
    __shared__ unsigned short Bs[2][128 * LDK];  // 2 x 16KB
    const int f32 = *dflag;
    const int tid = threadIdx.x;
    const int lane = tid & 63, wave = tid >> 6;  // wave 0..15
    const int b = blockIdx.z;
    const int n0 = blockIdx.x * 128, m0 = blockIdx.y * 128;
    const int wm = (wave & 3) * 32, wn = (wave >> 2) * 32;
    const int row16 = lane & 15, quad = lane >> 4;

    // ---- issue A stage (full K, pre-swizzled global source, 16 waves) ----
    {
        const unsigned short* Gb = Ab + (long)b * sA + (long)m0 * KK;
        if (KK == 256) {
            const int lrow = lane >> 5, slin = lane & 31;   // 2 rows / 1KB wave-call
#pragma unroll
            for (int t = 0; t < 4; ++t) {
                int rbase = wave * 8 + t * 2;
                int row = rbase + lrow;
                gload_lds16(Gb + (long)row * 256 + ((slin ^ (row & 7)) << 3),
                            As + rbase * 256);
            }
        } else {  // KK == 128
            const int lrow = lane >> 4, slin = lane & 15;   // 4 rows / 1KB wave-call
#pragma unroll
            for (int t = 0; t < 2; ++t) {
                int rbase = wave * 8 + t * 4;
                int row = rbase + lrow;
                gload_lds16(Gb + (long)row * 128 + ((slin ^ (row & 7)) << 3),
                            As + rbase * 128);
            }
        }
    }

    const unsigned short* Bbase[3] = {
        B0 + (long)b * sB + (long)n0 * KK,
        B1 + (long)b * sB + (long)n0 * KK,
        B2 + (long)b * sB + (long)n0 * KK };
    unsigned short* Cp[3] = { C0 + (long)b * sC, C1 + (long)b * sC, C2 + (long)b * sC };
    const void* biasp[3] = { bias0, bias1, bias2 };

    constexpr int NCH = KK / 64;       // chunks per sel
    constexpr int NQ = 3 * NCH;

    // ---- prologue: B chunk 0 of sel 0; drain A + B0 once ----
    stage_fast16(Bbase[0], KK, Bs[0], wave, lane);
    asm volatile("s_waitcnt vmcnt(0)" ::: "memory");
    __builtin_amdgcn_s_barrier();
    asm volatile("" ::: "memory");

    int cur = 0;
    f32x4 acc[2][2];
#pragma unroll 1
    for (int q = 0; q < NQ; ++q) {
        const int sel = q / NCH, c = q % NCH;
        if (c == 0) {
#pragma unroll
            for (int i = 0; i < 2; ++i)
#pragma unroll
                for (int j = 0; j < 2; ++j) acc[i][j] = {0.f, 0.f, 0.f, 0.f};
        }
        if (q + 1 < NQ) {
            const int sel2 = (q + 1) / NCH, c2 = (q + 1) % NCH;
            stage_fast16(Bbase[sel2] + c2 * 64, KK, Bs[cur ^ 1], wave, lane);
            asm volatile("s_waitcnt vmcnt(1)" ::: "memory");  // cur's B done; 1 prefetch in flight
        } else {
            asm volatile("s_waitcnt vmcnt(0)" ::: "memory");
        }
        __builtin_amdgcn_s_barrier();
        asm volatile("" ::: "memory");
        const unsigned short* Bsc = Bs[cur];
#pragma unroll
        for (int ks = 0; ks < 64; ks += 32) {
            const int kk = c * 64 + ks;
            const int saw = ((((kk >> 3) + quad) ^ (row16 & 7)) << 3);
            const int sbw = ((((ks >> 3) + quad) ^ (row16 & 7)) << 3);
            bf16x8 af[2], bfr[2];
#pragma unroll
            for (int i = 0; i < 2; ++i)
                af[i] = *(const bf16x8*)(As + (wm + i * 16 + row16) * KK + saw);
#pragma unroll
            for (int j = 0; j < 2; ++j)
                bfr[j] = *(const bf16x8*)(Bsc + (wn + j * 16 + row16) * LDK + sbw);
#pragma unroll
            for (int i = 0; i < 2; ++i)
#pragma unroll
                for (int j = 0; j < 2; ++j)
                    acc[i][j] = __builtin_amdgcn_mfma_f32_16x16x32_bf16(
                        af[i], bfr[j], acc[i][j], 0, 0, 0);
        }
        asm volatile("" ::: "memory");
        __builtin_amdgcn_s_barrier();   // all waves done reading Bs[cur] before overwrite
        asm volatile("" ::: "memory");
        cur ^= 1;
        if (c == NCH - 1) {
            unsigned short* C = Cp[sel];
            const void* bias = biasp[sel];
#pragma unroll
            for (int i = 0; i < 2; ++i) {
#pragma unroll
                for (int reg = 0; reg < 4; ++reg) {
                    const int gr = m0 + wm + i * 16 + quad * 4 + reg;
                    if (gr >= M) continue;
#pragma unroll
                    for (int j = 0; j < 2; ++j) {
                        const int gc = n0 + wn + j * 16 + row16;
                        float v = acc[i][j][reg];
                        if (bias) v += ldin(bias, gc, f32);
                        C[(long)gr * 256 + gc] = f2b(v);
                    }
                }
            }
        }
    }
}

// ---------- generic MFMA GEMM (ragged N / small shapes) ----------
template <typename OT>
DI void gemm_mfma_body(
    const unsigned short* __restrict__ A, const unsigned short* __restrict__ Bt,
    OT* __restrict__ C, const void* __restrict__ bias, int f32,
    int M, int N, int K, unsigned short* As, unsigned short* Bs)
{
    const int tid = threadIdx.x;
    const int m0 = blockIdx.y * 128, n0 = blockIdx.x * 128;
    const int lane = tid & 63, wave = tid >> 6;
    const int wm = (wave & 1) * 64, wn = (wave >> 1) * 64;
    const int row16 = lane & 15, quad = lane >> 4;
    const bool kfull = (K & 63) == 0;
    const bool fastA = kfull && (m0 + 128 <= M);
    const bool fastB = kfull && (n0 + 128 <= N);
    f32x4 acc[4][4];
#pragma unroll
    for (int i = 0; i < 4; ++i)
#pragma unroll
        for (int j = 0; j < 4; ++j) acc[i][j] = {0.f, 0.f, 0.f, 0.f};

    for (int k0 = 0; k0 < K; k0 += 64) {
        if (fastA) stage_fast(A + (long)m0 * K + k0, K, As, wave, lane);
        else       stage_slow(A, M, K, m0, k0, As, tid);
        if (fastB) stage_fast(Bt + (long)n0 * K + k0, K, Bs, wave, lane);
        else       stage_slow(Bt, N, K, n0, k0, Bs, tid);
        __syncthreads();
#pragma unroll
        for (int ks = 0; ks < 64; ks += 32) {
            const int sw = (((quad + (ks >> 3)) ^ (row16 & 7)) << 3);
            bf16x8 af[4], bfr[4];
#pragma unroll
            for (int i = 0; i < 4; ++i)
                af[i] = *(const bf16x8*)(As + (wm + i * 16 + row16) * LDK + sw);
#pragma unroll
            for (int j = 0; j < 4; ++j)
                bfr[j] = *(const bf16x8*)(Bs + (wn + j * 16 + row16) * LDK + sw);
#pragma unroll
            for (int i = 0; i < 4; ++i)
#pragma unroll
                for (int j = 0; j < 4; ++j)
                    acc[i][j] = __builtin_amdgcn_mfma_f32_16x16x32_bf16(
                        af[i], bfr[j], acc[i][j], 0, 0, 0);
        }
        __syncthreads();
    }
#pragma unroll
    for (int i = 0; i < 4; ++i) {
#pragma unroll
        for (int reg = 0; reg < 4; ++reg) {
            const int gr = m0 + wm + i * 16 + quad * 4 + reg;
            if (gr >= M) continue;
#pragma unroll
            for (int j = 0; j < 4; ++j) {
                const int gc = n0 + wn + j * 16 + row16;
                if (gc >= N) continue;
                float v = acc[i][j][reg];
                if (bias) v += ldin(bias, gc, f32);
                stval(&C[(long)gr * N + gc], v);
            }
        }
    }
}

// fused 3-way GEMM: blockIdx.z = sel*nbatch + b; sel picks (A,Bt,C,bias) quad
template <typename OT>
__global__ __launch_bounds__(256) void gemm_mfma3_k(
    const unsigned short* A0, const unsigned short* A1, const unsigned short* A2,
    const unsigned short* Bt0, const unsigned short* Bt1, const unsigned short* Bt2,
    OT* C0, OT* C1, OT* C2,
    const void* bias0, const void* bias1, const void* bias2,
    const int* __restrict__ dflag,
    int M, int N, int K, long sA, long sB, long sC, int nbatch)
{
    __shared__ unsigned short As[128 * LDK];
    __shared__ unsigned short Bs[128 * LDK];
    const int f32 = *dflag;
    const int sel = blockIdx.z / nbatch, b = blockIdx.z % nbatch;
    const unsigned short* A  = (sel == 0 ? A0 : sel == 1 ? A1 : A2) + (long)b * sA;
    const unsigned short* Bt = (sel == 0 ? Bt0 : sel == 1 ? Bt1 : Bt2) + (long)b * sB;
    OT* C = (sel == 0 ? C0 : sel == 1 ? C1 : C2) + (long)b * sC;
    const void* bias = sel == 0 ? bias0 : sel == 1 ? bias1 : bias2;
    gemm_mfma_body<OT>(A, Bt, C, bias, f32, M, N, K, As, Bs);
}

// ---------- CSR build: hist + hierarchical scan + weighted scatter ----------
__global__ __launch_bounds__(256) void hist_k(const int* __restrict__ ei, int E, int* __restrict__ cnt)
{
    int e = blockIdx.x * 256 + threadIdx.x;
    if (e < E) atomicAdd(&cnt[ei[E + e]], 1);
}
__global__ __launch_bounds__(256) void scan1_k(
    const int* __restrict__ cnt, int* __restrict__ off, int* __restrict__ bsum, int n)
{
    __shared__ int buf[256];
    int i = blockIdx.x * 256 + threadIdx.x;
    int v = (i < n) ? cnt[i] : 0;
    buf[threadIdx.x] = v;
    __syncthreads();
#pragma unroll
    for (int s = 1; s < 256; s <<= 1) {
        int t = (threadIdx.x >= s) ? buf[threadIdx.x - s] : 0;
        __syncthreads();
        buf[threadIdx.x] += t;
        __syncthreads();
    }
    if (i < n) off[i] = buf[threadIdx.x] - v;
    if (threadIdx.x == 255) bsum[blockIdx.x] = buf[255];
}
__global__ void scan2_k(int* __restrict__ bsum, int nb, int* __restrict__ total_dst)
{
    __shared__ int buf[256];
    int v = (threadIdx.x < nb) ? bsum[threadIdx.x] : 0;
    buf[threadIdx.x] = v;
    __syncthreads();
#pragma unroll
    for (int s = 1; s < 256; s <<= 1) {
        int t = (threadIdx.x >= s) ? buf[threadIdx.x - s] : 0;
        __syncthreads();
        buf[threadIdx.x] += t;
        __syncthreads();
    }
    if (threadIdx.x < nb) bsum[threadIdx.x] = buf[threadIdx.x] - v;  // exclusive
    if (threadIdx.x == 255) *total_dst = buf[255];
}
// scan3 also zeroes cnt so the next layer's hist needs no memset
__global__ __launch_bounds__(256) void scan3_k(
    int* __restrict__ off, int* __restrict__ cursor, const int* __restrict__ bsum,
    int* __restrict__ cnt, int n)
{
    int i = blockIdx.x * 256 + threadIdx.x;
    if (i < n) {
        int v = off[i] + bsum[blockIdx.x];
        off[i] = v;
        cursor[i] = v;
        cnt[i] = 0;
    }
}

// scatter + per-edge softmax weights (4 heads), emitting tgt-sorted streams
__global__ __launch_bounds__(256) void scatter0_k(
    const int* __restrict__ ei, const int* __restrict__ et, int E,
    int* __restrict__ cursor,
    const float* __restrict__ ajn, const float* __restrict__ ain,
    int* __restrict__ src_s, int* __restrict__ rt_s, float* __restrict__ w4_s)
{
    int e = blockIdx.x * 256 + threadIdx.x;
    if (e >= E) return;
    int src = ei[e], tgt = ei[E + e], r = et[e];
    int p = atomicAdd(&cursor[tgt], 1);
    src_s[p] = src; rt_s[p] = r;
    float4 a = *(const float4*)(ajn + (long)src * 20 + r * 4);
    float4 b = *(const float4*)(ain + (long)tgt * 20 + r * 4);
    float4 w;
    float s0 = a.x + b.x, s1 = a.y + b.y, s2 = a.z + b.z, s3 = a.w + b.w;
    s0 = s0 > 0.f ? s0 : 0.2f * s0;  s1 = s1 > 0.f ? s1 : 0.2f * s1;
    s2 = s2 > 0.f ? s2 : 0.2f * s2;  s3 = s3 > 0.f ? s3 : 0.2f * s3;
    w.x = expf(fminf(s0, 60.f)); w.y = expf(fminf(s1, 60.f));
    w.z = expf(fminf(s2, 60.f)); w.w = expf(fminf(s3, 60.f));
    *(float4*)(w4_s + (long)p * 4) = w;
}
__global__ __launch_bounds__(256) void scatter1_k(
    const int* __restrict__ ei, const int* __restrict__ et, int E,
    int* __restrict__ cursor,
    const float* __restrict__ ajn, const float* __restrict__ ain,
    int* __restrict__ src_s, int* __restrict__ rt_s, float* __restrict__ w_s)
{
    int e = blockIdx.x * 256 + threadIdx.x;
    if (e >= E) return;
    int src = ei[e], tgt = ei[E + e], r = et[e];
    int p = atomicAdd(&cursor[tgt], 1);
    src_s[p] = src; rt_s[p] = r;
    float s = ajn[(long)src * 5 + r] + ain[(long)tgt * 5 + r];
    s = s > 0.f ? s : 0.2f * s;
    w_s[p] = expf(fminf(s, 60.f));
}

// ---------- CSR aggregation, layer 0: one wave per tgt, sequential streams ----------
__global__ __launch_bounds__(256) void aggregate0_k(
    const int* __restrict__ src_s, const int* __restrict__ rt_s,
    const float* __restrict__ w4_s, const int* __restrict__ off,
    const unsigned short* __restrict__ hj,
    unsigned short* __restrict__ z, int Nn)
{
    int tgt = (int)((blockIdx.x * 256u + threadIdx.x) >> 6);
    int lane = threadIdx.x & 63;
    if (tgt >= Nn) return;
    int dd = lane * 4, h = lane >> 4;
    float acc[5][4] = {};
    float den[5] = {};
    int s = off[tgt], epd = off[tgt + 1];
    for (int i = s; i < epd; ++i) {
        int src = src_s[i];
        int r_e = rt_s[i];
        float wgt = w4_s[(long)i * 4 + h];
        ushort4 xj = *(const ushort4*)(hj + (long)src * 256 + dd);
        float x0 = b2f(xj.x), x1 = b2f(xj.y), x2 = b2f(xj.z), x3 = b2f(xj.w);
#pragma unroll
        for (int r = 0; r < 5; ++r) {
            float ws = (r == r_e) ? wgt : 0.f;
            den[r] += ws;
            acc[r][0] += ws * x0; acc[r][1] += ws * x1;
            acc[r][2] += ws * x2; acc[r][3] += ws * x3;
        }
    }
#pragma unroll
    for (int r = 0; r < 5; ++r) {
        float inv = 1.f / fmaxf(den[r], 1e-16f);
        ushort4 o;
        o.x = f2b(acc[r][0] * inv); o.y = f2b(acc[r][1] * inv);
        o.z = f2b(acc[r][2] * inv); o.w = f2b(acc[r][3] * inv);
        *(ushort4*)(z + ((long)r * Nn + tgt) * 256 + dd) = o;
    }
}

// ---------- CSR aggregation, layer 1 (H=1,C=40) ----------
__global__ __launch_bounds__(256) void aggregate1_k(
    const int* __restrict__ src_s, const int* __restrict__ rt_s,
    const float* __restrict__ w_s, const int* __restrict__ off,
    const unsigned short* __restrict__ hj,
    unsigned short* __restrict__ z, int Nn)
{
    int tgt = (int)((blockIdx.x * 256u + threadIdx.x) >> 6);
    int lane = threadIdx.x & 63;
    if (tgt >= Nn) return;
    bool act = lane < 40;
    float acc[5] = {};
    float den[5] = {};
    int s = off[tgt], epd = off[tgt + 1];
    for (int i = s; i < epd; ++i) {
        int src = src_s[i];
        int r_e = rt_s[i];
        float wgt = w_s[i];
        float xj = act ? b2f(hj[(long)src * 40 + lane]) : 0.f;
#pragma unroll
        for (int r = 0; r < 5; ++r) {
            float ws = (r == r_e) ? wgt : 0.f;
            den[r] += ws;
            acc[r] += ws * xj;
        }
    }
    if (act) {
#pragma unroll
        for (int r = 0; r < 5; ++r) {
            float inv = 1.f / fmaxf(den[r], 1e-16f);
            z[((long)r * Nn + tgt) * 40 + lane] = f2b(acc[r] * inv);
        }
    }
}

// ---------- fused relation attention, layer 0 (H=4,C=64): one wave per node ----------
__global__ __launch_bounds__(256) void fused_attn0_k(
    const unsigned short* __restrict__ qb, const unsigned short* __restrict__ kb,
    const unsigned short* __restrict__ vb, const void* __restrict__ wrel,
    unsigned short* __restrict__ x1, int n0, int nloc, int chq,
    const int* __restrict__ dflag)
{
    const int f32 = *dflag;
    int nl = (int)((blockIdx.x * 256u + threadIdx.x) >> 6);
    int lane = threadIdx.x & 63;
    if (nl >= nloc) return;
    int n = n0 + nl;
    int dd = lane * 4;
    float qf[5][4], kf[5][4];
#pragma unroll
    for (int r = 0; r < 5; ++r) {
        ushort4 qv = *(const ushort4*)(qb + ((long)r * chq + nl) * 256 + dd);
        ushort4 kv = *(const ushort4*)(kb + ((long)r * chq + nl) * 256 + dd);
        qf[r][0] = b2f(qv.x); qf[r][1] = b2f(qv.y); qf[r][2] = b2f(qv.z); qf[r][3] = b2f(qv.w);
        kf[r][0] = b2f(kv.x); kf[r][1] = b2f(kv.y); kf[r][2] = b2f(kv.z); kf[r][3] = b2f(kv.w);
    }
    float psi[5][5];
#pragma unroll
    for (int r = 0; r < 5; ++r)
#pragma unroll
        for (int s = 0; s < 5; ++s) {
            float p = qf[r][0] * kf[s][0] + qf[r][1] * kf[s][1] +
                      qf[r][2] * kf[s][2] + qf[r][3] * kf[s][3];
            p += __shfl_xor(p, 1, 64); p += __shfl_xor(p, 2, 64);
            p += __shfl_xor(p, 4, 64); p += __shfl_xor(p, 8, 64);
            psi[r][s] = p;
        }
    float pw[5] = {0.f, 0.f, 0.f, 0.f, 0.f};
#pragma unroll
    for (int r = 0; r < 5; ++r) {
        float rowsum = psi[r][0] + psi[r][1] + psi[r][2] + psi[r][3] + psi[r][4];
        float vals[5], m = NEGBIG;
#pragma unroll
        for (int s = 0; s < 5; ++s) {
            float v = (psi[r][s] == 0.f && rowsum != 0.f) ? NEGBIG : psi[r][s];
            vals[s] = v; m = fmaxf(m, v);
        }
        float es[5], sum = 0.f;
#pragma unroll
        for (int s = 0; s < 5; ++s) { es[s] = expf(vals[s] - m); sum += es[s]; }
        float wr = ldin(wrel, r, f32) / sum;
#pragma unroll
        for (int s = 0; s < 5; ++s) pw[s] += wr * es[s];
    }
    float acc[4] = {0.f, 0.f, 0.f, 0.f};
#pragma unroll
    for (int s = 0; s < 5; ++s) {
        ushort4 vv = *(const ushort4*)(vb + ((long)s * chq + nl) * 256 + dd);
        acc[0] += pw[s] * b2f(vv.x); acc[1] += pw[s] * b2f(vv.y);
        acc[2] += pw[s] * b2f(vv.z); acc[3] += pw[s] * b2f(vv.w);
    }
    ushort4* xp = (ushort4*)(x1 + (long)n * 256 + dd);
    ushort4 sv = *xp;
    sv.x = f2b(fmaxf(b2f(sv.x) + acc[0], 0.f));
    sv.y = f2b(fmaxf(b2f(sv.y) + acc[1], 0.f));
    sv.z = f2b(fmaxf(b2f(sv.z) + acc[2], 0.f));
    sv.w = f2b(fmaxf(b2f(sv.w) + acc[3], 0.f));
    *xp = sv;
}

// ---------- fused relation attention, layer 1 (H=1,C=40) + log_softmax -> d_out ----------
__global__ __launch_bounds__(256) void fused_attn1_k(
    const unsigned short* __restrict__ qb, const unsigned short* __restrict__ kb,
    const unsigned short* __restrict__ vb, const void* __restrict__ wrel,
    const unsigned short* __restrict__ self1, void* __restrict__ out, int N,
    const int* __restrict__ dflag)
{
    const int f32 = *dflag;
    int n = (int)((blockIdx.x * 256u + threadIdx.x) >> 6);
    int lane = threadIdx.x & 63;
    if (n >= N) return;
    bool act = lane < 40;
    float qf[5], kf[5];
#pragma unroll
    for (int r = 0; r < 5; ++r) {
        long o = ((long)r * N + n) * 40 + lane;
        qf[r] = act ? b2f(qb[o]) : 0.f;
        kf[r] = act ? b2f(kb[o]) : 0.f;
    }
    float psi[5][5];
#pragma unroll
    for (int r = 0; r < 5; ++r)
#pragma unroll
        for (int s = 0; s < 5; ++s) {
            float p = qf[r] * kf[s];
            p += __shfl_xor(p, 1, 64);  p += __shfl_xor(p, 2, 64);
            p += __shfl_xor(p, 4, 64);  p += __shfl_xor(p, 8, 64);
            p += __shfl_xor(p, 16, 64); p += __shfl_xor(p, 32, 64);
            psi[r][s] = p;
        }
    float pw[5] = {0.f, 0.f, 0.f, 0.f, 0.f};
#pragma unroll
    for (int r = 0; r < 5; ++r) {
        float rowsum = psi[r][0] + psi[r][1] + psi[r][2] + psi[r][3] + psi[r][4];
        float vals[5], m = NEGBIG;
#pragma unroll
        for (int s = 0; s < 5; ++s) {
            float v = (psi[r][s] == 0.f && rowsum != 0.f) ? NEGBIG : psi[r][s];
            vals[s] = v; m = fmaxf(m, v);
        }
        float es[5], sum = 0.f;
#pragma unroll
        for (int s = 0; s < 5; ++s) { es[s] = expf(vals[s] - m); sum += es[s]; }
        float wr = ldin(wrel, r, f32) / sum;
#pragma unroll
        for (int s = 0; s < 5; ++s) pw[s] += wr * es[s];
    }
    float val = NEGBIG;
    if (act) {
        float acc = 0.f;
#pragma unroll
        for (int s = 0; s < 5; ++s) acc += pw[s] * b2f(vb[((long)s * N + n) * 40 + lane]);
        val = b2f(self1[(long)n * 40 + lane]) + acc;
    }
    float m = val;
#pragma unroll
    for (int msk = 1; msk < 64; msk <<= 1) m = fmaxf(m, __shfl_xor(m, msk, 64));
    float e = act ? expf(val - m) : 0.f;
#pragma unroll
    for (int msk = 1; msk < 64; msk <<= 1) e += __shfl_xor(e, msk, 64);
    if (act) {
        float r = val - m - logf(e);
        long oidx = (long)n * 40 + lane;
        if (f32) ((float*)out)[oidx] = r;
        else     ((unsigned short*)out)[oidx] = f2b(r);
    }
}

// ---------- host ----------
extern "C" void kernel_launch(void* const* d_in, const int* in_sizes, int n_in,
                              void* d_out, int out_size, void* d_ws, size_t ws_size,
                              hipStream_t stream)
{
    const int* n_id = (const int*)d_in[0];
    const int* lidx = (const int*)d_in[1];
    const int* ei0  = (const int*)d_in[3];
    const int* et0  = (const int*)d_in[4];
    const int* ei1  = (const int*)d_in[5];
    const int* et1  = (const int*)d_in[6];
    const void* emb = d_in[7];
    const void* Wj0 = d_in[8];  const void* Wi0 = d_in[9];
    const void* aj0 = d_in[10]; const void* ai0 = d_in[11];
    const void* Wq0 = d_in[12]; const void* Wk0 = d_in[13]; const void* Wv0 = d_in[14];
    const void* sw0 = d_in[15]; const void* sb0 = d_in[16]; const void* Wr0 = d_in[17];
    const void* Wj1 = d_in[18]; const void* Wi1 = d_in[19];
    const void* aj1 = d_in[20]; const void* ai1 = d_in[21];
    const void* Wq1 = d_in[22]; const void* Wk1 = d_in[23]; const void* Wv1 = d_in[24];
    const void* sw1 = d_in[25]; const void* sb1 = d_in[26]; const void* Wr1 = d_in[27];
    const int E0 = in_sizes[4], E1 = in_sizes[6];

    auto al = [](size_t b) { return (b + 255) & ~(size_t)255; };

    // ---- persistent sizes (chunk-independent) ----
    const size_t P_total =
        al((size_t)R * N1 * HC0 * 2) +        // z0
        al((size_t)N1 * HC0 * 2) +            // x1
        2 * al((size_t)N1 * 20 * 4) +         // ajn0, ain0
        3 * al((size_t)(N1 + 1) * 4) +        // cnt, off, cursor
        al(256 * 4) +                         // bsum
        2 * al((size_t)E0 * 4) +              // src_s, rt_s
        al((size_t)E0 * 16) +                 // w4_s
        3 * al((size_t)HC0 * IN * 2) +        // wjt0/wit0/swt0
        3 * al((size_t)R * HC0 * HC0 * 2) +   // wqt0/wkt0/wvt0
        3 * al((size_t)C1 * HC0 * 2) +        // wjt1/wit1/swt1
        3 * al((size_t)R * C1 * C1 * 2) +     // wqt1/wkt1/wvt1
        2 * al(20 * 256 * 2) + 2 * al(5 * 40 * 2) +
        al(256);                              // dflag

    // chunk size: prefer 15000 (2 chunks, qc/kc/vc = 115MB, L3-resident) if ws fits
    int CH = 15000;
    {
        size_t need = 3 * al((size_t)R * CH * HC0 * 2) + P_total + (16u << 20);
        if (need > ws_size) CH = 7500;
    }
    const size_t QB = al((size_t)R * CH * HC0 * 2);   // one of qc/kc/vc

    // ---- workspace layout: overlay region V (qc|kc|vc) + persistent ----
    char* w = (char*)d_ws;
    // V phase 2 (qkv..attn0): qc | kc | vc
    unsigned short* qc = (unsigned short*)(w);
    unsigned short* kc = (unsigned short*)(w + QB);
    unsigned short* vc = (unsigned short*)(w + 2 * QB);
    // V phase 1 (start..aggregate0): x30k | hj0 | hi0  (38.4MB <= 3*QB)
    unsigned short* x30k = (unsigned short*)(w);
    unsigned short* hj0  = (unsigned short*)(w + al((size_t)N1 * IN * 2));
    unsigned short* hi0  = (unsigned short*)((char*)hj0 + al((size_t)N1 * HC0 * 2));
    // V phase 3 (post-attn0): layer-1 block (~28.2MB <= 3*QB)
    size_t o1 = 0;
    auto take1 = [&](size_t b) { char* p = w + o1; o1 += (b + 255) & ~(size_t)255; return p; };
    unsigned short* hj1   = (unsigned short*)take1((size_t)N2 * C1 * 2);
    unsigned short* hi1   = (unsigned short*)take1((size_t)N2 * C1 * 2);
    unsigned short* self1 = (unsigned short*)take1((size_t)N2 * C1 * 2);
    float* ajn1 = (float*)take1((size_t)N2 * R * 4);
    float* ain1 = (float*)take1((size_t)N2 * R * 4);
    unsigned short* z1  = (unsigned short*)take1((size_t)R * N2 * C1 * 2);
    unsigned short* q1b = (unsigned short*)take1((size_t)R * N2 * C1 * 2);
    unsigned short* k1b = (unsigned short*)take1((size_t)R * N2 * C1 * 2);
    unsigned short* v1b = (unsigned short*)take1((size_t)R * N2 * C1 * 2);
    // persistent
    size_t o = 3 * QB;
    auto take = [&](size_t b) { char* p = w + o; o += (b + 255) & ~(size_t)255; return p; };
    unsigned short* z0 = (unsigned short*)take((size_t)R * N1 * HC0 * 2);
    unsigned short* x1 = (unsigned short*)take((size_t)N1 * HC0 * 2);
    float* ajn0 = (float*)take((size_t)N1 * 20 * 4);
    float* ain0 = (float*)take((size_t)N1 * 20 * 4);
    int* cnt    = (int*)take((size_t)(N1 + 1) * 4);
    int* off    = (int*)take((size_t)(N1 + 1) * 4);
    int* cursor = (int*)take((size_t)(N1 + 1) * 4);
    int* bsum   = (int*)take(256 * 4);
    int* src_s  = (int*)take((size_t)E0 * 4);
    int* rt_s   = (int*)take((size_t)E0 * 4);
    float* w4_s = (float*)take((size_t)E0 * 16);
    unsigned short* wjt0 = (unsigned short*)take((size_t)HC0 * IN * 2);
    unsigned short* wit0 = (unsigned short*)take((size_t)HC0 * IN * 2);
    unsigned short* swt0 = (unsigned short*)take((size_t)HC0 * IN * 2);
    unsigned short* wqt0 = (unsigned short*)take((size_t)R * HC0 * HC0 * 2);
    unsigned short* wkt0 = (unsigned short*)take((size_t)R * HC0 * HC0 * 2);
    unsigned short* wvt0 = (unsigned short*)take((size_t)R * HC0 * HC0 * 2);
    unsigned short* wjt1 = (unsigned short*)take((size_t)C1 * HC0 * 2);
    unsigned short* wit1 = (unsigned short*)take((size_t)C1 * HC0 * 2);
    unsigned short* swt1 = (unsigned short*)take((size_t)C1 * HC0 * 2);
    unsigned short* wqt1 = (unsigned short*)take((size_t)R * C1 * C1 * 2);
    unsigned short* wkt1 = (unsigned short*)take((size_t)R * C1 * C1 * 2);
    unsigned short* wvt1 = (unsigned short*)take((size_t)R * C1 * C1 * 2);
    unsigned short* atA0j = (unsigned short*)take(20 * 256 * 2);
    unsigned short* atA0i = (unsigned short*)take(20 * 256 * 2);
    unsigned short* atA1j = (unsigned short*)take(5 * 40 * 2);
    unsigned short* atA1i = (unsigned short*)take(5 * 40 * 2);
    int* dflag = (int*)take(256);

    // ---- dtype flavor detection ----
    detect_k<<<1, 64, 0, stream>>>(emb, dflag);

    // ---- fused prep: 12 transposes + att matrices + cnt zero (1 launch) ----
    {
        PrepJobs J;
        const void* srcs[12] = {Wj0, Wi0, sw0, Wq0, Wk0, Wv0, Wj1, Wi1, sw1, Wq1, Wk1, Wv1};
        unsigned short* dsts[12] = {wjt0, wit0, swt0, wqt0, wkt0, wvt0,
                                    wjt1, wit1, swt1, wqt1, wkt1, wvt1};
        int Ks[12] = {IN, IN, IN, HC0, HC0, HC0, HC0, HC0, HC0, C1, C1, C1};
        int Ns[12] = {HC0, HC0, HC0, HC0, HC0, HC0, C1, C1, C1, C1, C1, C1};
        int pers[12] = {IN * HC0, IN * HC0, IN * HC0,
                        R * HC0 * HC0, R * HC0 * HC0, R * HC0 * HC0,
                        HC0 * C1, HC0 * C1, HC0 * C1,
                        R * C1 * C1, R * C1 * C1, R * C1 * C1};
        for (int i = 0; i < 12; ++i) {
            J.src[i] = srcs[i]; J.dst[i] = dsts[i];
            J.K[i] = Ks[i]; J.N[i] = Ns[i]; J.per[i] = pers[i];
        }
        int xb = (R * HC0 * HC0 + 255) / 256;   // 1280, covers all jobs + cnt zero
        prep_all_k<<<dim3((unsigned)xb, 13), 256, 0, stream>>>(
            J, aj0, ai0, aj1, ai1, atA0j, atA0i, atA1j, atA1i, cnt, N1 + 1, dflag);
    }

    // ---- layer 0: features (A-resident 16-wave pipelined MFMA) + alpha (generic) ----
    gather_k<<<(int)(((long)N1 * IN + 255) / 256), 256, 0, stream>>>(n_id, lidx, emb, x30k, N1, dflag);
    gemm_ares5_k<128><<<dim3(2, (N1 + 127) / 128, 1), 1024, 0, stream>>>(
        x30k, wjt0, wit0, swt0, hj0, hi0, x1, nullptr, nullptr, sb0,
        dflag, N1, 0, 0, 0);
    gemm_mfma3_k<float><<<dim3(1, (N1 + 127) / 128, 2), 256, 0, stream>>>(
        hj0, hi0, hi0, atA0j, atA0i, atA0i, ajn0, ain0, ain0, nullptr, nullptr, nullptr,
        dflag, N1, 20, HC0, 0, 0, 0, 1);

    // ---- layer 0: CSR (tgt-sorted streams with fused weights) + aggregation ----
    hist_k<<<(E0 + 255) / 256, 256, 0, stream>>>(ei0, E0, cnt);
    {
        int nb = (N1 + 255) / 256;
        scan1_k<<<nb, 256, 0, stream>>>(cnt, off, bsum, N1);
        scan2_k<<<1, 256, 0, stream>>>(bsum, nb, off + N1);
        scan3_k<<<nb, 256, 0, stream>>>(off, cursor, bsum, cnt, N1);  // zeroes cnt
    }
    scatter0_k<<<(E0 + 255) / 256, 256, 0, stream>>>(ei0, et0, E0, cursor, ajn0, ain0, src_s, rt_s, w4_s);
    aggregate0_k<<<(N1 + 3) / 4, 256, 0, stream>>>(src_s, rt_s, w4_s, off, hj0, z0, N1);

    // ---- layer 0: chunked q/k/v (A-resident 16-wave MFMA) + relation attention ----
    {
        const int nch = N1 / CH;
        for (int c = 0; c < nch; ++c) {
            const unsigned short* zc = z0 + (long)c * CH * HC0;
            gemm_ares5_k<256><<<dim3(2, (CH + 127) / 128, R), 1024, 0, stream>>>(
                zc, wqt0, wkt0, wvt0, qc, kc, vc, nullptr, nullptr, nullptr,
                dflag, CH, (long)N1 * HC0, (long)HC0 * HC0, (long)CH * HC0);
            fused_attn0_k<<<(CH + 3) / 4, 256, 0, stream>>>(qc, kc, vc, Wr0, x1, c * CH, CH, CH, dflag);
        }
    }

    // ---- layer 1: features + alpha (MFMA) ----
    gemm_mfma3_k<unsigned short><<<dim3(1, (N2 + 127) / 128, 3), 256, 0, stream>>>(
        x1, x1, x1, wjt1, wit1, swt1, hj1, hi1, self1, nullptr, nullptr, sb1,
        dflag, N2, C1, HC0, 0, 0, 0, 1);
    gemm_mfma3_k<float><<<dim3(1, (N2 + 127) / 128, 2), 256, 0, stream>>>(
        hj1, hi1, hi1, atA1j, atA1i, atA1i, ajn1, ain1, ain1, nullptr, nullptr, nullptr,
        dflag, N2, 5, C1, 0, 0, 0, 1);

    // ---- layer 1: CSR + aggregation ----
    hist_k<<<(E1 + 255) / 256, 256, 0, stream>>>(ei1, E1, cnt);   // cnt zeroed by scan3
    {
        int nb = (N2 + 255) / 256;
        scan1_k<<<nb, 256, 0, stream>>>(cnt, off, bsum, N2);
        scan2_k<<<1, 256, 0, stream>>>(bsum, nb, off + N2);
        scan3_k<<<nb, 256, 0, stream>>>(off, cursor, bsum, cnt, N2);
    }
    scatter1_k<<<(E1 + 255) / 256, 256, 0, stream>>>(ei1, et1, E1, cursor, ajn1, ain1, src_s, rt_s, w4_s);
    aggregate1_k<<<(N2 + 3) / 4, 256, 0, stream>>>(src_s, rt_s, w4_s, off, hj1, z1, N2);

    // ---- layer 1: q/k/v + attention + log_softmax ----
    {
        long sA = (long)N2 * C1, sB = (long)C1 * C1, sC = (long)N2 * C1;
        gemm_mfma3_k<unsigned short><<<dim3(1, (N2 + 127) / 128, 3 * R), 256, 0, stream>>>(
            z1, z1, z1, wqt1, wkt1, wvt1, q1b, k1b, v1b, nullptr, nullptr, nullptr,
            dflag, N2, C1, C1, sA, sB, sC, R);
    }
    fused_attn1_k<<<(N2 + 3) / 4, 256, 0, stream>>>(q1b, k1b, v1b, Wr1, self1, d_out, N2, dflag);
}

// Round 8
// 603.392 us; speedup vs baseline: 1.1102x; 1.1102x over previous
//
#include <hip/hip_runtime.h>
#include <hip/hip_bf16.h>

#define DI __device__ __forceinline__

// ---------- bf16 helpers (raw ushort bits) ----------
DI float b2f(unsigned short u) {
    union { unsigned int i; float f; } x; x.i = ((unsigned int)u) << 16; return x.f;
}
DI unsigned short f2b(float f) {
    union { float f; unsigned int i; } x; x.f = f;
    unsigned int r = x.i + 0x7fff + ((x.i >> 16) & 1);  // RNE
    return (unsigned short)(r >> 16);
}
// flavor-aware input load: f32!=0 -> fp32 array, else bf16 array
DI float ldin(const void* p, long i, int f32) {
    return f32 ? ((const float*)p)[i] : b2f(((const unsigned short*)p)[i]);
}
DI void stval(float* p, float v) { *p = v; }
DI void stval(unsigned short* p, float v) { *p = f2b(v); }

// ---------- constants ----------
static constexpr int N1 = 30000, N2 = 15000, R = 5;
static constexpr int IN = 128, HC0 = 256, C1 = 40;
static constexpr float NEGBIG = -1e30f;    // finite "-inf" (NaN-proof masking)
static constexpr int LDK = 64;             // LDS K-stride (shorts); row = 128B

typedef short bf16x8 __attribute__((ext_vector_type(8)));
typedef float f32x4 __attribute__((ext_vector_type(4)));

// ---------- dtype flavor detection (fp32 read as bf16 -> huge/NaN exponents) ----------
__global__ void detect_k(const void* emb, int* flag)
{
    int lane = threadIdx.x;   // 64 threads
    int bad = 0;
    for (int j = 0; j < 4; ++j) {
        float f = b2f(((const unsigned short*)emb)[lane * 4 + j]);
        if (!(fabsf(f) < 1e8f)) bad = 1;   // catches NaN too
    }
    unsigned long long anybad = __ballot(bad != 0);
    if (lane == 0) *flag = (anybad != 0ull) ? 1 : 0;
}

// ---------- fused prep: 12 weight transposes + alpha-GEMM B matrices + cnt zero ----------
// transpose job y: dst[b][n][k] = bf16(src[b][k][n])
struct PrepJobs {
    const void* src[12];
    unsigned short* dst[12];
    int K[12];
    int N[12];
    int per[12];
};
__global__ __launch_bounds__(256) void prep_all_k(
    PrepJobs J,
    const void* aj0, const void* ai0, const void* aj1, const void* ai1,
    unsigned short* A0j, unsigned short* A0i, unsigned short* A1j, unsigned short* A1i,
    int* __restrict__ cnt, int cntn,
    const int* __restrict__ dflag)
{
    const int f32 = *dflag;
    const int y = blockIdx.y;
    long t = (long)blockIdx.x * 256 + threadIdx.x;
    if (y < 12) {
        if (t >= J.per[y]) return;
        const int K = J.K[y], N = J.N[y];
        long kn = (long)K * N;
        long b = t / kn, rem = t % kn;
        long k = rem / N, n = rem % N;          // t fastest over n -> coalesced read
        J.dst[y][(b * N + n) * K + k] = f2b(ldin(J.src[y], t, f32));
    } else {
        // att matrices: A0j[j=r*4+h][k] = attj0[r,h,c] if k==h*64+c else 0 (20x256)
        if (t < 20 * 256) {
            int j = (int)(t >> 8), k = (int)(t & 255);
            int h = j & 3, r = j >> 2;
            bool on = (k >> 6) == h;
            A0j[t] = f2b(on ? ldin(aj0, r * 256 + k, f32) : 0.f);
            A0i[t] = f2b(on ? ldin(ai0, r * 256 + k, f32) : 0.f);
        }
        if (t < 5 * 40) {
            A1j[t] = f2b(ldin(aj1, t, f32));
            A1i[t] = f2b(ldin(ai1, t, f32));
        }
        if (t < cntn) cnt[t] = 0;
    }
}

// ---------- gather x[:N1] = bf16(emb[lidx[n_id[n]]]) ----------
__global__ __launch_bounds__(256) void gather_k(
    const int* __restrict__ n_id, const int* __restrict__ lidx,
    const void* __restrict__ emb, unsigned short* __restrict__ x, int rows,
    const int* __restrict__ dflag)
{
    const int f32 = *dflag;
    long t = (long)blockIdx.x * 256 + threadIdx.x;
    long n = t >> 7, d = t & 127;
    if (n >= rows) return;
    long row = lidx[n_id[n]];
    x[n * IN + d] = f2b(ldin(emb, row * IN + d, f32));
}

// ---------- MFMA GEMM cores ----------
// LDS layouts are XOR-swizzled (T2, G4): element (row, 16B-slot s) lives at
// slot s ^ (row&7). global_load_lds writes linearly (lane*16B), so fast staging
// pre-swizzles the per-lane GLOBAL source address (rule #21); slow staging
// swizzles its direct LDS writes; fragment reads apply the same XOR.

DI void gload_lds16(const unsigned short* src, unsigned short* dst)
{
    __builtin_amdgcn_global_load_lds(
        (const __attribute__((address_space(1))) unsigned int*)src,
        (__attribute__((address_space(3))) unsigned int*)dst, 16, 0, 0);
}

// Stage one [128 rows][64 cols] K-chunk with 4 waves (generic GEMM tiles)
DI void stage_fast(const unsigned short* __restrict__ G, int K,
                   unsigned short* S, int wave, int lane)
{
    const int p = lane >> 3;                       // row-within-8 (== row&7)
    const int scol = ((lane & 7) ^ p) * 8;         // pre-swizzled source col (shorts)
#pragma unroll
    for (int t = 0; t < 4; ++t) {
        int row = t * 32 + wave * 8 + p;
        gload_lds16(G + (long)row * K + scol, S + (t * 32 + wave * 8) * LDK);
    }
}
// Stage one [128 rows][64 cols] K-chunk with 8 waves (2 calls/lane)
DI void stage_fast8(const unsigned short* __restrict__ G, int K,
                    unsigned short* S, int wave, int lane)
{
    const int p = lane >> 3;
    const int scol = ((lane & 7) ^ p) * 8;
#pragma unroll
    for (int t = 0; t < 2; ++t) {
        int row = wave * 16 + t * 8 + p;           // row&7 == p
        gload_lds16(G + (long)row * K + scol, S + (wave * 16 + t * 8) * LDK);
    }
}
// Slow staging (boundary rows / ragged K): guarded, zero-filled, swizzled writes
DI void stage_slow(const unsigned short* __restrict__ G, int rows, int K,
                   int r0, int k0, unsigned short* S, int tid)
{
    const int sr = tid >> 1, sq = (tid & 1) * 32;
    const int sx = sr & 7;
    unsigned short* drow = S + sr * LDK;
    const unsigned short* g = G + (long)(r0 + sr) * K + k0 + sq;
    const bool rowok = (r0 + sr) < rows;
    const int s0 = sq >> 3;                        // base 16B slot (0 or 4)
    if (rowok && (k0 + sq + 32) <= K) {
        const uint4* gv = (const uint4*)g;
        uint4 a = gv[0], b = gv[1], c = gv[2], d = gv[3];
        *(uint4*)(drow + (((s0 + 0) ^ sx) << 3)) = a;
        *(uint4*)(drow + (((s0 + 1) ^ sx) << 3)) = b;
        *(uint4*)(drow + (((s0 + 2) ^ sx) << 3)) = c;
        *(uint4*)(drow + (((s0 + 3) ^ sx) << 3)) = d;
    } else if (!rowok) {
        uint4 zz = {0u, 0u, 0u, 0u};
        *(uint4*)(drow + (((s0 + 0) ^ sx) << 3)) = zz;
        *(uint4*)(drow + (((s0 + 1) ^ sx) << 3)) = zz;
        *(uint4*)(drow + (((s0 + 2) ^ sx) << 3)) = zz;
        *(uint4*)(drow + (((s0 + 3) ^ sx) << 3)) = zz;
    } else {
#pragma unroll 8
        for (int j = 0; j < 32; ++j) {
            int col = sq + j;
            int k = k0 + col;
            int widx = (((col >> 3) ^ sx) << 3) | (col & 7);
            drow[widx] = (k < K) ? g[j] : (unsigned short)0;
        }
    }
}

// ---------- A-resident 3-way GEMM, 8-wave (r6 proven config) ----------
// 512 threads (8 waves), 128x128 tile, K template {128,256}.
// A-tile (shared by all 3 sel) staged to LDS ONCE full-K; per sel only the 16KB
// B K-chunk is staged per K-step (simple 2-barrier phases, single Bs buffer).
// LDS: K=256 -> 80KB (2 blocks/CU = 16 waves/CU); K=128 -> 48KB (3 blocks/CU).
// No early returns (all 512 threads reach every __syncthreads). stageA may read
// up to 127 rows past M for boundary tiles -- callers guarantee trailing
// workspace; garbage rows never written out (gr<M guard; MFMA rows independent).
template <int KK>
__global__ __launch_bounds__(512) void gemm_ares4_k(
    const unsigned short* __restrict__ Ab,
    const unsigned short* B0, const unsigned short* B1, const unsigned short* B2,
    unsigned short* C0, unsigned short* C1, unsigned short* C2,
    const void* bias0, const void* bias1, const void* bias2,
    const int* __restrict__ dflag,
    int M, long sA, long sB, long sC)
{
    __shared__ unsigned short As[128 * KK];      // 64KB (K=256) / 32KB (K=128)
    __shared__ unsigned short Bs[128 * LDK];     // 16KB
    const int f32 = *dflag;
    const int tid = threadIdx.x;
    const int lane = tid & 63, wave = tid >> 6;  // wave 0..7
    const int b = blockIdx.z;
    const int n0 = blockIdx.x * 128, m0 = blockIdx.y * 128;
    const int wm = (wave & 1) * 64, wn = (wave >> 1) * 32;
    const int row16 = lane & 15, quad = lane >> 4;

    // ---- issue A stage (full K, pre-swizzled global source, 8 waves) ----
    {
        const unsigned short* Gb = Ab + (long)b * sA + (long)m0 * KK;
        if (KK == 256) {
            const int lrow = lane >> 5, slin = lane & 31;   // 2 rows / 1KB wave-call
#pragma unroll
            for (int t = 0; t < 8; ++t) {
                int rbase = wave * 16 + t * 2;
                int row = rbase + lrow;
                gload_lds16(Gb + (long)row * 256 + ((slin ^ (row & 7)) << 3),
                            As + rbase * 256);
            }
        } else {  // KK == 128
            const int lrow = lane >> 4, slin = lane & 15;   // 4 rows / 1KB wave-call
#pragma unroll
            for (int t = 0; t < 4; ++t) {
                int rbase = wave * 16 + t * 4;
                int row = rbase + lrow;
                gload_lds16(Gb + (long)row * 128 + ((slin ^ (row & 7)) << 3),
                            As + rbase * 128);
            }
        }
    }
    // A-stage drains at the first __syncthreads below (compiler emits vmcnt(0)).

#pragma unroll 1
    for (int sel = 0; sel < 3; ++sel) {
        const unsigned short* Bt = (sel == 0 ? B0 : sel == 1 ? B1 : B2)
                                   + (long)b * sB + (long)n0 * KK;
        unsigned short* C = (sel == 0 ? C0 : sel == 1 ? C1 : C2) + (long)b * sC;
        const void* bias = sel == 0 ? bias0 : sel == 1 ? bias1 : bias2;
        f32x4 acc[4][2];
#pragma unroll
        for (int i = 0; i < 4; ++i)
#pragma unroll
            for (int j = 0; j < 2; ++j) acc[i][j] = {0.f, 0.f, 0.f, 0.f};

        for (int k0 = 0; k0 < KK; k0 += 64) {
            stage_fast8(Bt + k0, KK, Bs, wave, lane);
            __syncthreads();   // drains B stage (and A stage on first pass)
#pragma unroll
            for (int ks = 0; ks < 64; ks += 32) {
                const int kk = k0 + ks;
                const int saw = ((((kk >> 3) + quad) ^ (row16 & 7)) << 3);
                const int sbw = ((((ks >> 3) + quad) ^ (row16 & 7)) << 3);
                bf16x8 af[4], bfr[2];
#pragma unroll
                for (int i = 0; i < 4; ++i)
                    af[i] = *(const bf16x8*)(As + (wm + i * 16 + row16) * KK + saw);
#pragma unroll
                for (int j = 0; j < 2; ++j)
                    bfr[j] = *(const bf16x8*)(Bs + (wn + j * 16 + row16) * LDK + sbw);
#pragma unroll
                for (int i = 0; i < 4; ++i)
#pragma unroll
                    for (int j = 0; j < 2; ++j)
                        acc[i][j] = __builtin_amdgcn_mfma_f32_16x16x32_bf16(
                            af[i], bfr[j], acc[i][j], 0, 0, 0);
            }
            __syncthreads();   // all waves done with Bs before next chunk overwrites
        }
#pragma unroll
        for (int i = 0; i < 4; ++i) {
#pragma unroll
            for (int reg = 0; reg < 4; ++reg) {
                const int gr = m0 + wm + i * 16 + quad * 4 + reg;
                if (gr >= M) continue;
#pragma unroll
                for (int j = 0; j < 2; ++j) {
                    const int gc = n0 + wn + j * 16 + row16;
                    float v = acc[i][j][reg];
                    if (bias) v += ldin(bias, gc, f32);
                    C[(long)gr * 256 + gc] = f2b(v);
                }
            }
        }
    }
}

// ---------- generic MFMA GEMM (ragged N / small shapes) ----------
template <typename OT>
DI void gemm_mfma_body(
    const unsigned short* __restrict__ A, const unsigned short* __restrict__ Bt,
    OT* __restrict__ C, const void* __restrict__ bias, int f32,
    int M, int N, int K, unsigned short* As, unsigned short* Bs)
{
    const int tid = threadIdx.x;
    const int m0 = blockIdx.y * 128, n0 = blockIdx.x * 128;
    const int lane = tid & 63, wave = tid >> 6;
    const int wm = (wave & 1) * 64, wn = (wave >> 1) * 64;
    const int row16 = lane & 15, quad = lane >> 4;
    const bool kfull = (K & 63) == 0;
    const bool fastA = kfull && (m0 + 128 <= M);
    const bool fastB = kfull && (n0 + 128 <= N);
    f32x4 acc[4][4];
#pragma unroll
    for (int i = 0; i < 4; ++i)
#pragma unroll
        for (int j = 0; j < 4; ++j) acc[i][j] = {0.f, 0.f, 0.f, 0.f};

    for (int k0 = 0; k0 < K; k0 += 64) {
        if (fastA) stage_fast(A + (long)m0 * K + k0, K, As, wave, lane);
        else       stage_slow(A, M, K, m0, k0, As, tid);
        if (fastB) stage_fast(Bt + (long)n0 * K + k0, K, Bs, wave, lane);
        else       stage_slow(Bt, N, K, n0, k0, Bs, tid);
        __syncthreads();
#pragma unroll
        for (int ks = 0; ks < 64; ks += 32) {
            const int sw = (((quad + (ks >> 3)) ^ (row16 & 7)) << 3);
            bf16x8 af[4], bfr[4];
#pragma unroll
            for (int i = 0; i < 4; ++i)
                af[i] = *(const bf16x8*)(As + (wm + i * 16 + row16) * LDK + sw);
#pragma unroll
            for (int j = 0; j < 4; ++j)
                bfr[j] = *(const bf16x8*)(Bs + (wn + j * 16 + row16) * LDK + sw);
#pragma unroll
            for (int i = 0; i < 4; ++i)
#pragma unroll
                for (int j = 0; j < 4; ++j)
                    acc[i][j] = __builtin_amdgcn_mfma_f32_16x16x32_bf16(
                        af[i], bfr[j], acc[i][j], 0, 0, 0);
        }
        __syncthreads();
    }
#pragma unroll
    for (int i = 0; i < 4; ++i) {
#pragma unroll
        for (int reg = 0; reg < 4; ++reg) {
            const int gr = m0 + wm + i * 16 + quad * 4 + reg;
            if (gr >= M) continue;
#pragma unroll
            for (int j = 0; j < 4; ++j) {
                const int gc = n0 + wn + j * 16 + row16;
                if (gc >= N) continue;
                float v = acc[i][j][reg];
                if (bias) v += ldin(bias, gc, f32);
                stval(&C[(long)gr * N + gc], v);
            }
        }
    }
}

// fused 3-way GEMM: blockIdx.z = sel*nbatch + b; sel picks (A,Bt,C,bias) quad
template <typename OT>
__global__ __launch_bounds__(256) void gemm_mfma3_k(
    const unsigned short* A0, const unsigned short* A1, const unsigned short* A2,
    const unsigned short* Bt0, const unsigned short* Bt1, const unsigned short* Bt2,
    OT* C0, OT* C1, OT* C2,
    const void* bias0, const void* bias1, const void* bias2,
    const int* __restrict__ dflag,
    int M, int N, int K, long sA, long sB, long sC, int nbatch)
{
    __shared__ unsigned short As[128 * LDK];
    __shared__ unsigned short Bs[128 * LDK];
    const int f32 = *dflag;
    const int sel = blockIdx.z / nbatch, b = blockIdx.z % nbatch;
    const unsigned short* A  = (sel == 0 ? A0 : sel == 1 ? A1 : A2) + (long)b * sA;
    const unsigned short* Bt = (sel == 0 ? Bt0 : sel == 1 ? Bt1 : Bt2) + (long)b * sB;
    OT* C = (sel == 0 ? C0 : sel == 1 ? C1 : C2) + (long)b * sC;
    const void* bias = sel == 0 ? bias0 : sel == 1 ? bias1 : bias2;
    gemm_mfma_body<OT>(A, Bt, C, bias, f32, M, N, K, As, Bs);
}

// ---------- CSR build: hist + hierarchical scan + weighted scatter ----------
__global__ __launch_bounds__(256) void hist_k(const int* __restrict__ ei, int E, int* __restrict__ cnt)
{
    int e = blockIdx.x * 256 + threadIdx.x;
    if (e < E) atomicAdd(&cnt[ei[E + e]], 1);
}
__global__ __launch_bounds__(256) void scan1_k(
    const int* __restrict__ cnt, int* __restrict__ off, int* __restrict__ bsum, int n)
{
    __shared__ int buf[256];
    int i = blockIdx.x * 256 + threadIdx.x;
    int v = (i < n) ? cnt[i] : 0;
    buf[threadIdx.x] = v;
    __syncthreads();
#pragma unroll
    for (int s = 1; s < 256; s <<= 1) {
        int t = (threadIdx.x >= s) ? buf[threadIdx.x - s] : 0;
        __syncthreads();
        buf[threadIdx.x] += t;
        __syncthreads();
    }
    if (i < n) off[i] = buf[threadIdx.x] - v;
    if (threadIdx.x == 255) bsum[blockIdx.x] = buf[255];
}
__global__ void scan2_k(int* __restrict__ bsum, int nb, int* __restrict__ total_dst)
{
    __shared__ int buf[256];
    int v = (threadIdx.x < nb) ? bsum[threadIdx.x] : 0;
    buf[threadIdx.x] = v;
    __syncthreads();
#pragma unroll
    for (int s = 1; s < 256; s <<= 1) {
        int t = (threadIdx.x >= s) ? buf[threadIdx.x - s] : 0;
        __syncthreads();
        buf[threadIdx.x] += t;
        __syncthreads();
    }
    if (threadIdx.x < nb) bsum[threadIdx.x] = buf[threadIdx.x] - v;  // exclusive
    if (threadIdx.x == 255) *total_dst = buf[255];
}
// scan3 also zeroes cnt so the next layer's hist needs no memset
__global__ __launch_bounds__(256) void scan3_k(
    int* __restrict__ off, int* __restrict__ cursor, const int* __restrict__ bsum,
    int* __restrict__ cnt, int n)
{
    int i = blockIdx.x * 256 + threadIdx.x;
    if (i < n) {
        int v = off[i] + bsum[blockIdx.x];
        off[i] = v;
        cursor[i] = v;
        cnt[i] = 0;
    }
}

// scatter + per-edge softmax weights (4 heads), emitting tgt-sorted streams
__global__ __launch_bounds__(256) void scatter0_k(
    const int* __restrict__ ei, const int* __restrict__ et, int E,
    int* __restrict__ cursor,
    const float* __restrict__ ajn, const float* __restrict__ ain,
    int* __restrict__ src_s, int* __restrict__ rt_s, float* __restrict__ w4_s)
{
    int e = blockIdx.x * 256 + threadIdx.x;
    if (e >= E) return;
    int src = ei[e], tgt = ei[E + e], r = et[e];
    int p = atomicAdd(&cursor[tgt], 1);
    src_s[p] = src; rt_s[p] = r;
    float4 a = *(const float4*)(ajn + (long)src * 20 + r * 4);
    float4 b = *(const float4*)(ain + (long)tgt * 20 + r * 4);
    float4 w;
    float s0 = a.x + b.x, s1 = a.y + b.y, s2 = a.z + b.z, s3 = a.w + b.w;
    s0 = s0 > 0.f ? s0 : 0.2f * s0;  s1 = s1 > 0.f ? s1 : 0.2f * s1;
    s2 = s2 > 0.f ? s2 : 0.2f * s2;  s3 = s3 > 0.f ? s3 : 0.2f * s3;
    w.x = expf(fminf(s0, 60.f)); w.y = expf(fminf(s1, 60.f));
    w.z = expf(fminf(s2, 60.f)); w.w = expf(fminf(s3, 60.f));
    *(float4*)(w4_s + (long)p * 4) = w;
}
__global__ __launch_bounds__(256) void scatter1_k(
    const int* __restrict__ ei, const int* __restrict__ et, int E,
    int* __restrict__ cursor,
    const float* __restrict__ ajn, const float* __restrict__ ain,
    int* __restrict__ src_s, int* __restrict__ rt_s, float* __restrict__ w_s)
{
    int e = blockIdx.x * 256 + threadIdx.x;
    if (e >= E) return;
    int src = ei[e], tgt = ei[E + e], r = et[e];
    int p = atomicAdd(&cursor[tgt], 1);
    src_s[p] = src; rt_s[p] = r;
    float s = ajn[(long)src * 5 + r] + ain[(long)tgt * 5 + r];
    s = s > 0.f ? s : 0.2f * s;
    w_s[p] = expf(fminf(s, 60.f));
}

// ---------- CSR aggregation, layer 0: one wave per tgt, sequential streams ----------
__global__ __launch_bounds__(256) void aggregate0_k(
    const int* __restrict__ src_s, const int* __restrict__ rt_s,
    const float* __restrict__ w4_s, const int* __restrict__ off,
    const unsigned short* __restrict__ hj,
    unsigned short* __restrict__ z, int Nn)
{
    int tgt = (int)((blockIdx.x * 256u + threadIdx.x) >> 6);
    int lane = threadIdx.x & 63;
    if (tgt >= Nn) return;
    int dd = lane * 4, h = lane >> 4;
    float acc[5][4] = {};
    float den[5] = {};
    int s = off[tgt], epd = off[tgt + 1];
    for (int i = s; i < epd; ++i) {
        int src = src_s[i];
        int r_e = rt_s[i];
        float wgt = w4_s[(long)i * 4 + h];
        ushort4 xj = *(const ushort4*)(hj + (long)src * 256 + dd);
        float x0 = b2f(xj.x), x1 = b2f(xj.y), x2 = b2f(xj.z), x3 = b2f(xj.w);
#pragma unroll
        for (int r = 0; r < 5; ++r) {
            float ws = (r == r_e) ? wgt : 0.f;
            den[r] += ws;
            acc[r][0] += ws * x0; acc[r][1] += ws * x1;
            acc[r][2] += ws * x2; acc[r][3] += ws * x3;
        }
    }
#pragma unroll
    for (int r = 0; r < 5; ++r) {
        float inv = 1.f / fmaxf(den[r], 1e-16f);
        ushort4 o;
        o.x = f2b(acc[r][0] * inv); o.y = f2b(acc[r][1] * inv);
        o.z = f2b(acc[r][2] * inv); o.w = f2b(acc[r][3] * inv);
        *(ushort4*)(z + ((long)r * Nn + tgt) * 256 + dd) = o;
    }
}

// ---------- CSR aggregation, layer 1 (H=1,C=40) ----------
__global__ __launch_bounds__(256) void aggregate1_k(
    const int* __restrict__ src_s, const int* __restrict__ rt_s,
    const float* __restrict__ w_s, const int* __restrict__ off,
    const unsigned short* __restrict__ hj,
    unsigned short* __restrict__ z, int Nn)
{
    int tgt = (int)((blockIdx.x * 256u + threadIdx.x) >> 6);
    int lane = threadIdx.x & 63;
    if (tgt >= Nn) return;
    bool act = lane < 40;
    float acc[5] = {};
    float den[5] = {};
    int s = off[tgt], epd = off[tgt + 1];
    for (int i = s; i < epd; ++i) {
        int src = src_s[i];
        int r_e = rt_s[i];
        float wgt = w_s[i];
        float xj = act ? b2f(hj[(long)src * 40 + lane]) : 0.f;
#pragma unroll
        for (int r = 0; r < 5; ++r) {
            float ws = (r == r_e) ? wgt : 0.f;
            den[r] += ws;
            acc[r] += ws * xj;
        }
    }
    if (act) {
#pragma unroll
        for (int r = 0; r < 5; ++r) {
            float inv = 1.f / fmaxf(den[r], 1e-16f);
            z[((long)r * Nn + tgt) * 40 + lane] = f2b(acc[r] * inv);
        }
    }
}

// ---------- fused relation attention, layer 0 (H=4,C=64): one wave per node ----------
__global__ __launch_bounds__(256) void fused_attn0_k(
    const unsigned short* __restrict__ qb, const unsigned short* __restrict__ kb,
    const unsigned short* __restrict__ vb, const void* __restrict__ wrel,
    unsigned short* __restrict__ x1, int n0, int nloc, int chq,
    const int* __restrict__ dflag)
{
    const int f32 = *dflag;
    int nl = (int)((blockIdx.x * 256u + threadIdx.x) >> 6);
    int lane = threadIdx.x & 63;
    if (nl >= nloc) return;
    int n = n0 + nl;
    int dd = lane * 4;
    float qf[5][4], kf[5][4];
#pragma unroll
    for (int r = 0; r < 5; ++r) {
        ushort4 qv = *(const ushort4*)(qb + ((long)r * chq + nl) * 256 + dd);
        ushort4 kv = *(const ushort4*)(kb + ((long)r * chq + nl) * 256 + dd);
        qf[r][0] = b2f(qv.x); qf[r][1] = b2f(qv.y); qf[r][2] = b2f(qv.z); qf[r][3] = b2f(qv.w);
        kf[r][0] = b2f(kv.x); kf[r][1] = b2f(kv.y); kf[r][2] = b2f(kv.z); kf[r][3] = b2f(kv.w);
    }
    float psi[5][5];
#pragma unroll
    for (int r = 0; r < 5; ++r)
#pragma unroll
        for (int s = 0; s < 5; ++s) {
            float p = qf[r][0] * kf[s][0] + qf[r][1] * kf[s][1] +
                      qf[r][2] * kf[s][2] + qf[r][3] * kf[s][3];
            p += __shfl_xor(p, 1, 64); p += __shfl_xor(p, 2, 64);
            p += __shfl_xor(p, 4, 64); p += __shfl_xor(p, 8, 64);
            psi[r][s] = p;
        }
    float pw[5] = {0.f, 0.f, 0.f, 0.f, 0.f};
#pragma unroll
    for (int r = 0; r < 5; ++r) {
        float rowsum = psi[r][0] + psi[r][1] + psi[r][2] + psi[r][3] + psi[r][4];
        float vals[5], m = NEGBIG;
#pragma unroll
        for (int s = 0; s < 5; ++s) {
            float v = (psi[r][s] == 0.f && rowsum != 0.f) ? NEGBIG : psi[r][s];
            vals[s] = v; m = fmaxf(m, v);
        }
        float es[5], sum = 0.f;
#pragma unroll
        for (int s = 0; s < 5; ++s) { es[s] = expf(vals[s] - m); sum += es[s]; }
        float wr = ldin(wrel, r, f32) / sum;
#pragma unroll
        for (int s = 0; s < 5; ++s) pw[s] += wr * es[s];
    }
    float acc[4] = {0.f, 0.f, 0.f, 0.f};
#pragma unroll
    for (int s = 0; s < 5; ++s) {
        ushort4 vv = *(const ushort4*)(vb + ((long)s * chq + nl) * 256 + dd);
        acc[0] += pw[s] * b2f(vv.x); acc[1] += pw[s] * b2f(vv.y);
        acc[2] += pw[s] * b2f(vv.z); acc[3] += pw[s] * b2f(vv.w);
    }
    ushort4* xp = (ushort4*)(x1 + (long)n * 256 + dd);
    ushort4 sv = *xp;
    sv.x = f2b(fmaxf(b2f(sv.x) + acc[0], 0.f));
    sv.y = f2b(fmaxf(b2f(sv.y) + acc[1], 0.f));
    sv.z = f2b(fmaxf(b2f(sv.z) + acc[2], 0.f));
    sv.w = f2b(fmaxf(b2f(sv.w) + acc[3], 0.f));
    *xp = sv;
}

// ---------- fused relation attention, layer 1 (H=1,C=40) + log_softmax -> d_out ----------
__global__ __launch_bounds__(256) void fused_attn1_k(
    const unsigned short* __restrict__ qb, const unsigned short* __restrict__ kb,
    const unsigned short* __restrict__ vb, const void* __restrict__ wrel,
    const unsigned short* __restrict__ self1, void* __restrict__ out, int N,
    const int* __restrict__ dflag)
{
    const int f32 = *dflag;
    int n = (int)((blockIdx.x * 256u + threadIdx.x) >> 6);
    int lane = threadIdx.x & 63;
    if (n >= N) return;
    bool act = lane < 40;
    float qf[5], kf[5];
#pragma unroll
    for (int r = 0; r < 5; ++r) {
        long o = ((long)r * N + n) * 40 + lane;
        qf[r] = act ? b2f(qb[o]) : 0.f;
        kf[r] = act ? b2f(kb[o]) : 0.f;
    }
    float psi[5][5];
#pragma unroll
    for (int r = 0; r < 5; ++r)
#pragma unroll
        for (int s = 0; s < 5; ++s) {
            float p = qf[r] * kf[s];
            p += __shfl_xor(p, 1, 64);  p += __shfl_xor(p, 2, 64);
            p += __shfl_xor(p, 4, 64);  p += __shfl_xor(p, 8, 64);
            p += __shfl_xor(p, 16, 64); p += __shfl_xor(p, 32, 64);
            psi[r][s] = p;
        }
    float pw[5] = {0.f, 0.f, 0.f, 0.f, 0.f};
#pragma unroll
    for (int r = 0; r < 5; ++r) {
        float rowsum = psi[r][0] + psi[r][1] + psi[r][2] + psi[r][3] + psi[r][4];
        float vals[5], m = NEGBIG;
#pragma unroll
        for (int s = 0; s < 5; ++s) {
            float v = (psi[r][s] == 0.f && rowsum != 0.f) ? NEGBIG : psi[r][s];
            vals[s] = v; m = fmaxf(m, v);
        }
        float es[5], sum = 0.f;
#pragma unroll
        for (int s = 0; s < 5; ++s) { es[s] = expf(vals[s] - m); sum += es[s]; }
        float wr = ldin(wrel, r, f32) / sum;
#pragma unroll
        for (int s = 0; s < 5; ++s) pw[s] += wr * es[s];
    }
    float val = NEGBIG;
    if (act) {
        float acc = 0.f;
#pragma unroll
        for (int s = 0; s < 5; ++s) acc += pw[s] * b2f(vb[((long)s * N + n) * 40 + lane]);
        val = b2f(self1[(long)n * 40 + lane]) + acc;
    }
    float m = val;
#pragma unroll
    for (int msk = 1; msk < 64; msk <<= 1) m = fmaxf(m, __shfl_xor(m, msk, 64));
    float e = act ? expf(val - m) : 0.f;
#pragma unroll
    for (int msk = 1; msk < 64; msk <<= 1) e += __shfl_xor(e, msk, 64);
    if (act) {
        float r = val - m - logf(e);
        long oidx = (long)n * 40 + lane;
        if (f32) ((float*)out)[oidx] = r;
        else     ((unsigned short*)out)[oidx] = f2b(r);
    }
}

// ---------- host ----------
extern "C" void kernel_launch(void* const* d_in, const int* in_sizes, int n_in,
                              void* d_out, int out_size, void* d_ws, size_t ws_size,
                              hipStream_t stream)
{
    const int* n_id = (const int*)d_in[0];
    const int* lidx = (const int*)d_in[1];
    const int* ei0  = (const int*)d_in[3];
    const int* et0  = (const int*)d_in[4];
    const int* ei1  = (const int*)d_in[5];
    const int* et1  = (const int*)d_in[6];
    const void* emb = d_in[7];
    const void* Wj0 = d_in[8];  const void* Wi0 = d_in[9];
    const void* aj0 = d_in[10]; const void* ai0 = d_in[11];
    const void* Wq0 = d_in[12]; const void* Wk0 = d_in[13]; const void* Wv0 = d_in[14];
    const void* sw0 = d_in[15]; const void* sb0 = d_in[16]; const void* Wr0 = d_in[17];
    const void* Wj1 = d_in[18]; const void* Wi1 = d_in[19];
    const void* aj1 = d_in[20]; const void* ai1 = d_in[21];
    const void* Wq1 = d_in[22]; const void* Wk1 = d_in[23]; const void* Wv1 = d_in[24];
    const void* sw1 = d_in[25]; const void* sb1 = d_in[26]; const void* Wr1 = d_in[27];
    const int E0 = in_sizes[4], E1 = in_sizes[6];

    auto al = [](size_t b) { return (b + 255) & ~(size_t)255; };

    // ---- persistent sizes (chunk-independent) ----
    const size_t P_total =
        al((size_t)R * N1 * HC0 * 2) +        // z0
        al((size_t)N1 * HC0 * 2) +            // x1
        2 * al((size_t)N1 * 20 * 4) +         // ajn0, ain0
        3 * al((size_t)(N1 + 1) * 4) +        // cnt, off, cursor
        al(256 * 4) +                         // bsum
        2 * al((size_t)E0 * 4) +              // src_s, rt_s
        al((size_t)E0 * 16) +                 // w4_s
        3 * al((size_t)HC0 * IN * 2) +        // wjt0/wit0/swt0
        3 * al((size_t)R * HC0 * HC0 * 2) +   // wqt0/wkt0/wvt0
        3 * al((size_t)C1 * HC0 * 2) +        // wjt1/wit1/swt1
        3 * al((size_t)R * C1 * C1 * 2) +     // wqt1/wkt1/wvt1
        2 * al(20 * 256 * 2) + 2 * al(5 * 40 * 2) +
        al(256);                              // dflag

    // chunk size: prefer full N1 (single QKV launch, best tail), else 15000, else 7500
    int CH = N1;
    {
        auto need = [&](int ch) {
            return 3 * al((size_t)R * ch * HC0 * 2) + P_total + (16u << 20);
        };
        if (need(CH) > ws_size) CH = 15000;
        if (need(CH) > ws_size) CH = 7500;
    }
    const size_t QB = al((size_t)R * CH * HC0 * 2);   // one of qc/kc/vc

    // ---- workspace layout: overlay region V (qc|kc|vc) + persistent ----
    char* w = (char*)d_ws;
    // V phase 2 (qkv..attn0): qc | kc | vc
    unsigned short* qc = (unsigned short*)(w);
    unsigned short* kc = (unsigned short*)(w + QB);
    unsigned short* vc = (unsigned short*)(w + 2 * QB);
    // V phase 1 (start..aggregate0): x30k | hj0 | hi0  (38.4MB <= 3*QB)
    unsigned short* x30k = (unsigned short*)(w);
    unsigned short* hj0  = (unsigned short*)(w + al((size_t)N1 * IN * 2));
    unsigned short* hi0  = (unsigned short*)((char*)hj0 + al((size_t)N1 * HC0 * 2));
    // V phase 3 (post-attn0): layer-1 block (~28.2MB <= 3*QB)
    size_t o1 = 0;
    auto take1 = [&](size_t b) { char* p = w + o1; o1 += (b + 255) & ~(size_t)255; return p; };
    unsigned short* hj1   = (unsigned short*)take1((size_t)N2 * C1 * 2);
    unsigned short* hi1   = (unsigned short*)take1((size_t)N2 * C1 * 2);
    unsigned short* self1 = (unsigned short*)take1((size_t)N2 * C1 * 2);
    float* ajn1 = (float*)take1((size_t)N2 * R * 4);
    float* ain1 = (float*)take1((size_t)N2 * R * 4);
    unsigned short* z1  = (unsigned short*)take1((size_t)R * N2 * C1 * 2);
    unsigned short* q1b = (unsigned short*)take1((size_t)R * N2 * C1 * 2);
    unsigned short* k1b = (unsigned short*)take1((size_t)R * N2 * C1 * 2);
    unsigned short* v1b = (unsigned short*)take1((size_t)R * N2 * C1 * 2);
    // persistent
    size_t o = 3 * QB;
    auto take = [&](size_t b) { char* p = w + o; o += (b + 255) & ~(size_t)255; return p; };
    unsigned short* z0 = (unsigned short*)take((size_t)R * N1 * HC0 * 2);
    unsigned short* x1 = (unsigned short*)take((size_t)N1 * HC0 * 2);
    float* ajn0 = (float*)take((size_t)N1 * 20 * 4);
    float* ain0 = (float*)take((size_t)N1 * 20 * 4);
    int* cnt    = (int*)take((size_t)(N1 + 1) * 4);
    int* off    = (int*)take((size_t)(N1 + 1) * 4);
    int* cursor = (int*)take((size_t)(N1 + 1) * 4);
    int* bsum   = (int*)take(256 * 4);
    int* src_s  = (int*)take((size_t)E0 * 4);
    int* rt_s   = (int*)take((size_t)E0 * 4);
    float* w4_s = (float*)take((size_t)E0 * 16);
    unsigned short* wjt0 = (unsigned short*)take((size_t)HC0 * IN * 2);
    unsigned short* wit0 = (unsigned short*)take((size_t)HC0 * IN * 2);
    unsigned short* swt0 = (unsigned short*)take((size_t)HC0 * IN * 2);
    unsigned short* wqt0 = (unsigned short*)take((size_t)R * HC0 * HC0 * 2);
    unsigned short* wkt0 = (unsigned short*)take((size_t)R * HC0 * HC0 * 2);
    unsigned short* wvt0 = (unsigned short*)take((size_t)R * HC0 * HC0 * 2);
    unsigned short* wjt1 = (unsigned short*)take((size_t)C1 * HC0 * 2);
    unsigned short* wit1 = (unsigned short*)take((size_t)C1 * HC0 * 2);
    unsigned short* swt1 = (unsigned short*)take((size_t)C1 * HC0 * 2);
    unsigned short* wqt1 = (unsigned short*)take((size_t)R * C1 * C1 * 2);
    unsigned short* wkt1 = (unsigned short*)take((size_t)R * C1 * C1 * 2);
    unsigned short* wvt1 = (unsigned short*)take((size_t)R * C1 * C1 * 2);
    unsigned short* atA0j = (unsigned short*)take(20 * 256 * 2);
    unsigned short* atA0i = (unsigned short*)take(20 * 256 * 2);
    unsigned short* atA1j = (unsigned short*)take(5 * 40 * 2);
    unsigned short* atA1i = (unsigned short*)take(5 * 40 * 2);
    int* dflag = (int*)take(256);

    // ---- dtype flavor detection ----
    detect_k<<<1, 64, 0, stream>>>(emb, dflag);

    // ---- fused prep: 12 transposes + att matrices + cnt zero (1 launch) ----
    {
        PrepJobs J;
        const void* srcs[12] = {Wj0, Wi0, sw0, Wq0, Wk0, Wv0, Wj1, Wi1, sw1, Wq1, Wk1, Wv1};
        unsigned short* dsts[12] = {wjt0, wit0, swt0, wqt0, wkt0, wvt0,
                                    wjt1, wit1, swt1, wqt1, wkt1, wvt1};
        int Ks[12] = {IN, IN, IN, HC0, HC0, HC0, HC0, HC0, HC0, C1, C1, C1};
        int Ns[12] = {HC0, HC0, HC0, HC0, HC0, HC0, C1, C1, C1, C1, C1, C1};
        int pers[12] = {IN * HC0, IN * HC0, IN * HC0,
                        R * HC0 * HC0, R * HC0 * HC0, R * HC0 * HC0,
                        HC0 * C1, HC0 * C1, HC0 * C1,
                        R * C1 * C1, R * C1 * C1, R * C1 * C1};
        for (int i = 0; i < 12; ++i) {
            J.src[i] = srcs[i]; J.dst[i] = dsts[i];
            J.K[i] = Ks[i]; J.N[i] = Ns[i]; J.per[i] = pers[i];
        }
        int xb = (R * HC0 * HC0 + 255) / 256;   // 1280, covers all jobs + cnt zero
        prep_all_k<<<dim3((unsigned)xb, 13), 256, 0, stream>>>(
            J, aj0, ai0, aj1, ai1, atA0j, atA0i, atA1j, atA1i, cnt, N1 + 1, dflag);
    }

    // ---- layer 0: features (A-resident 8-wave MFMA) + alpha (generic) ----
    gather_k<<<(int)(((long)N1 * IN + 255) / 256), 256, 0, stream>>>(n_id, lidx, emb, x30k, N1, dflag);
    gemm_ares4_k<128><<<dim3(2, (N1 + 127) / 128, 1), 512, 0, stream>>>(
        x30k, wjt0, wit0, swt0, hj0, hi0, x1, nullptr, nullptr, sb0,
        dflag, N1, 0, 0, 0);
    gemm_mfma3_k<float><<<dim3(1, (N1 + 127) / 128, 2), 256, 0, stream>>>(
        hj0, hi0, hi0, atA0j, atA0i, atA0i, ajn0, ain0, ain0, nullptr, nullptr, nullptr,
        dflag, N1, 20, HC0, 0, 0, 0, 1);

    // ---- layer 0: CSR (tgt-sorted streams with fused weights) + aggregation ----
    hist_k<<<(E0 + 255) / 256, 256, 0, stream>>>(ei0, E0, cnt);
    {
        int nb = (N1 + 255) / 256;
        scan1_k<<<nb, 256, 0, stream>>>(cnt, off, bsum, N1);
        scan2_k<<<1, 256, 0, stream>>>(bsum, nb, off + N1);
        scan3_k<<<nb, 256, 0, stream>>>(off, cursor, bsum, cnt, N1);  // zeroes cnt
    }
    scatter0_k<<<(E0 + 255) / 256, 256, 0, stream>>>(ei0, et0, E0, cursor, ajn0, ain0, src_s, rt_s, w4_s);
    aggregate0_k<<<(N1 + 3) / 4, 256, 0, stream>>>(src_s, rt_s, w4_s, off, hj0, z0, N1);

    // ---- layer 0: chunked q/k/v (A-resident 8-wave MFMA) + relation attention ----
    {
        const int nch = N1 / CH;
        for (int c = 0; c < nch; ++c) {
            const unsigned short* zc = z0 + (long)c * CH * HC0;
            gemm_ares4_k<256><<<dim3(2, (CH + 127) / 128, R), 512, 0, stream>>>(
                zc, wqt0, wkt0, wvt0, qc, kc, vc, nullptr, nullptr, nullptr,
                dflag, CH, (long)N1 * HC0, (long)HC0 * HC0, (long)CH * HC0);
            fused_attn0_k<<<(CH + 3) / 4, 256, 0, stream>>>(qc, kc, vc, Wr0, x1, c * CH, CH, CH, dflag);
        }
    }

    // ---- layer 1: features + alpha (MFMA) ----
    gemm_mfma3_k<unsigned short><<<dim3(1, (N2 + 127) / 128, 3), 256, 0, stream>>>(
        x1, x1, x1, wjt1, wit1, swt1, hj1, hi1, self1, nullptr, nullptr, sb1,
        dflag, N2, C1, HC0, 0, 0, 0, 1);
    gemm_mfma3_k<float><<<dim3(1, (N2 + 127) / 128, 2), 256, 0, stream>>>(
        hj1, hi1, hi1, atA1j, atA1i, atA1i, ajn1, ain1, ain1, nullptr, nullptr, nullptr,
        dflag, N2, 5, C1, 0, 0, 0, 1);

    // ---- layer 1: CSR + aggregation ----
    hist_k<<<(E1 + 255) / 256, 256, 0, stream>>>(ei1, E1, cnt);   // cnt zeroed by scan3
    {
        int nb = (N2 + 255) / 256;
        scan1_k<<<nb, 256, 0, stream>>>(cnt, off, bsum, N2);
        scan2_k<<<1, 256, 0, stream>>>(bsum, nb, off + N2);
        scan3_k<<<nb, 256, 0, stream>>>(off, cursor, bsum, cnt, N2);
    }
    scatter1_k<<<(E1 + 255) / 256, 256, 0, stream>>>(ei1, et1, E1, cursor, ajn1, ain1, src_s, rt_s, w4_s);
    aggregate1_k<<<(N2 + 3) / 4, 256, 0, stream>>>(src_s, rt_s, w4_s, off, hj1, z1, N2);

    // ---- layer 1: q/k/v + attention + log_softmax ----
    {
        long sA = (long)N2 * C1, sB = (long)C1 * C1, sC = (long)N2 * C1;
        gemm_mfma3_k<unsigned short><<<dim3(1, (N2 + 127) / 128, 3 * R), 256, 0, stream>>>(
            z1, z1, z1, wqt1, wkt1, wvt1, q1b, k1b, v1b, nullptr, nullptr, nullptr,
            dflag, N2, C1, C1, sA, sB, sC, R);
    }
    fused_attn1_k<<<(N2 + 3) / 4, 256, 0, stream>>>(q1b, k1b, v1b, Wr1, self1, d_out, N2, dflag);
}